// Round 1
// 1650.451 us; speedup vs baseline: 1.6610x; 1.6610x over previous
//
#include <hip/hip_runtime.h>

typedef unsigned short u16;

// ---- problem constants ----
#define BB 256
#define LL 200
#define NN 512
#define DD 64
#define HH 128

// d_out element offsets (fp32 elements)
#define MU_OFF   26214400
#define LV_OFF   26230784
#define ZT_OFF   26247168
#define ZD_OFF   29523968

typedef __attribute__((ext_vector_type(8))) short bf8v;   // 8 bf16 (4 VGPRs) MFMA frag
typedef __attribute__((ext_vector_type(4))) short bf4v;   // 4 bf16 (8B)
typedef __attribute__((ext_vector_type(4))) float f32x4;  // MFMA accum

__device__ __forceinline__ float bf2f(u16 u) {
    union { unsigned int i; float f; } v; v.i = ((unsigned int)u) << 16; return v.f;
}
__device__ __forceinline__ u16 f2bf(float f) {
    union { float f; unsigned int u; } v; v.f = f;
    unsigned int r = v.u + 0x7FFFu + ((v.u >> 16) & 1u);   // RNE
    return (u16)(r >> 16);
}
// Runtime input-dtype probe: tvec[199] as bf16 reads ~1.99 if inputs are
// bf16; if fp32, u16[199] is the high half of float tvec[99] (~0.988).
__device__ __forceinline__ bool detect_f32(const void* tvec) {
    float v = bf2f(((const u16*)tvec)[199]);
    return !(v > 1.5f && v < 2.5f);
}
__device__ __forceinline__ float loadf(const void* p, long idx, bool f32m) {
    return f32m ? ((const float*)p)[idx] : bf2f(((const u16*)p)[idx]);
}

// ---------------------------------------------------------------------------
// Kernel 1: encoder. 2 batch rows per block, 512 threads, fp32 VALU.
// (unchanged from previous round)
// ---------------------------------------------------------------------------
__global__ __launch_bounds__(512) void enc_kernel(
    const void* __restrict__ x_seq, const void* __restrict__ tvec,
    const void* __restrict__ epsp,
    const void* __restrict__ ew1, const void* __restrict__ eb1,
    const void* __restrict__ ew2, const void* __restrict__ eb2,
    const void* __restrict__ ew3, const void* __restrict__ eb3,
    const void* __restrict__ muw, const void* __restrict__ mub,
    const void* __restrict__ lvw, const void* __restrict__ lvb,
    float* __restrict__ out, float* __restrict__ z0f)
{
    __shared__ __align__(16) float xs[2][512];
    __shared__ __align__(16) float h1[2][512];
    __shared__ __align__(16) float h2[2][256];
    __shared__ __align__(16) float h3[2][128];
    __shared__ float muv[2][64], lvv[2][64];
    const bool m = detect_f32(tvec);
    const int t = threadIdx.x;
    const int b0 = blockIdx.x * 2;

    xs[0][t] = loadf(x_seq, (long)(b0 + 0) * 102400 + t, m);
    xs[1][t] = loadf(x_seq, (long)(b0 + 1) * 102400 + t, m);
    __syncthreads();

    // L1: 512 -> 512, one neuron per thread
    {
        float a0 = 0.f, a1 = 0.f;
        const float4* x0v = (const float4*)xs[0];
        const float4* x1v = (const float4*)xs[1];
        #pragma unroll 4
        for (int j4 = 0; j4 < 128; ++j4) {
            float4 xa = x0v[j4], xb = x1v[j4];
            float w0 = loadf(ew1, (4 * j4 + 0) * 512 + t, m);
            float w1v = loadf(ew1, (4 * j4 + 1) * 512 + t, m);
            float w2v = loadf(ew1, (4 * j4 + 2) * 512 + t, m);
            float w3v = loadf(ew1, (4 * j4 + 3) * 512 + t, m);
            a0 += xa.x * w0 + xa.y * w1v + xa.z * w2v + xa.w * w3v;
            a1 += xb.x * w0 + xb.y * w1v + xb.z * w2v + xb.w * w3v;
        }
        float bb = loadf(eb1, t, m);
        h1[0][t] = fmaxf(a0 + bb, 0.f);
        h1[1][t] = fmaxf(a1 + bb, 0.f);
    }
    __syncthreads();

    // L2: 512 -> 256, 2 threads per neuron
    {
        const int i = t >> 1, s = t & 1;
        float a0 = 0.f, a1 = 0.f;
        const float4* p0 = (const float4*)&h1[0][s * 256];
        const float4* p1 = (const float4*)&h1[1][s * 256];
        #pragma unroll 4
        for (int j4 = 0; j4 < 64; ++j4) {
            float4 xa = p0[j4], xb = p1[j4];
            int j = s * 256 + 4 * j4;
            float w0 = loadf(ew2, (j + 0) * 256 + i, m);
            float w1v = loadf(ew2, (j + 1) * 256 + i, m);
            float w2v = loadf(ew2, (j + 2) * 256 + i, m);
            float w3v = loadf(ew2, (j + 3) * 256 + i, m);
            a0 += xa.x * w0 + xa.y * w1v + xa.z * w2v + xa.w * w3v;
            a1 += xb.x * w0 + xb.y * w1v + xb.z * w2v + xb.w * w3v;
        }
        a0 += __shfl_xor(a0, 1);
        a1 += __shfl_xor(a1, 1);
        if (s == 0) {
            float bb = loadf(eb2, i, m);
            h2[0][i] = fmaxf(a0 + bb, 0.f);
            h2[1][i] = fmaxf(a1 + bb, 0.f);
        }
    }
    __syncthreads();

    // L3: 256 -> 128, 4 threads per neuron
    {
        const int i = t >> 2, s = t & 3;
        float a0 = 0.f, a1 = 0.f;
        const float4* p0 = (const float4*)&h2[0][s * 64];
        const float4* p1 = (const float4*)&h2[1][s * 64];
        #pragma unroll 4
        for (int j4 = 0; j4 < 16; ++j4) {
            float4 xa = p0[j4], xb = p1[j4];
            int j = s * 64 + 4 * j4;
            float w0 = loadf(ew3, (j + 0) * 128 + i, m);
            float w1v = loadf(ew3, (j + 1) * 128 + i, m);
            float w2v = loadf(ew3, (j + 2) * 128 + i, m);
            float w3v = loadf(ew3, (j + 3) * 128 + i, m);
            a0 += xa.x * w0 + xa.y * w1v + xa.z * w2v + xa.w * w3v;
            a1 += xb.x * w0 + xb.y * w1v + xb.z * w2v + xb.w * w3v;
        }
        a0 += __shfl_xor(a0, 1); a0 += __shfl_xor(a0, 2);
        a1 += __shfl_xor(a1, 1); a1 += __shfl_xor(a1, 2);
        if (s == 0) {
            float bb = loadf(eb3, i, m);
            h3[0][i] = fmaxf(a0 + bb, 0.f);
            h3[1][i] = fmaxf(a1 + bb, 0.f);
        }
    }
    __syncthreads();

    // mu / logvar heads: 128 -> 64 each
    {
        const int o = t >> 2, s = t & 3;
        const void* wp; const void* bp; int oc;
        if (o < 64) { wp = muw; bp = mub; oc = o; }
        else        { wp = lvw; bp = lvb; oc = o - 64; }
        float a0 = 0.f, a1 = 0.f;
        const float4* p0 = (const float4*)&h3[0][s * 32];
        const float4* p1 = (const float4*)&h3[1][s * 32];
        #pragma unroll
        for (int j4 = 0; j4 < 8; ++j4) {
            float4 xa = p0[j4], xb = p1[j4];
            int j = s * 32 + 4 * j4;
            float w0 = loadf(wp, (j + 0) * 64 + oc, m);
            float w1v = loadf(wp, (j + 1) * 64 + oc, m);
            float w2v = loadf(wp, (j + 2) * 64 + oc, m);
            float w3v = loadf(wp, (j + 3) * 64 + oc, m);
            a0 += xa.x * w0 + xa.y * w1v + xa.z * w2v + xa.w * w3v;
            a1 += xb.x * w0 + xb.y * w1v + xb.z * w2v + xb.w * w3v;
        }
        a0 += __shfl_xor(a0, 1); a0 += __shfl_xor(a0, 2);
        a1 += __shfl_xor(a1, 1); a1 += __shfl_xor(a1, 2);
        if (s == 0) {
            float bb = loadf(bp, oc, m);
            if (o < 64) { muv[0][oc] = a0 + bb; muv[1][oc] = a1 + bb; }
            else        { lvv[0][oc] = a0 + bb; lvv[1][oc] = a1 + bb; }
        }
    }
    __syncthreads();

    if (t < 128) {
        int r = t >> 6, d = t & 63;
        float mm = muv[r][d], l = lvv[r][d];
        float z = mm + expf(0.5f * l) * loadf(epsp, (b0 + r) * 64 + d, m);
        z0f[(b0 + r) * 64 + d] = z;
        out[MU_OFF + (b0 + r) * 64 + d] = mm;
        out[LV_OFF + (b0 + r) * 64 + d] = l;
    }
}

// ---------------------------------------------------------------------------
// Kernel 2: ODE RK4 integrator (unchanged from previous round).
// ---------------------------------------------------------------------------
__global__ __launch_bounds__(512) void ode_kernel(
    const void* __restrict__ tvec,
    const void* __restrict__ w1, const void* __restrict__ b1,
    const void* __restrict__ w2, const void* __restrict__ b2,
    const void* __restrict__ w3, const void* __restrict__ b3,
    const void* __restrict__ lng, const void* __restrict__ lnb,
    const float* __restrict__ z0f,
    float* __restrict__ zt_out, float* __restrict__ zd_out)
{
    __shared__ __align__(16) float zc[64];
    __shared__ __align__(16) float h1f[128];
    __shared__ __align__(16) float h2f[128];
    __shared__ float dzf[64];
    __shared__ float dts[200];

    const bool mdt = detect_f32(tvec);
    const int t = threadIdx.x;
    const int b = blockIdx.x;
    const int i1 = t >> 2, s1 = t & 3;
    const int i3 = t >> 3, s3 = t & 7;

    float w1r[16], w2r[32], w3r[16];
    #pragma unroll
    for (int jj = 0; jj < 16; ++jj)
        w1r[jj] = loadf(w1, (16 * s1 + jj) * 128 + i1, mdt);
    #pragma unroll
    for (int jq = 0; jq < 8; ++jq) {
        int base = 32 * s1 + ((4 * jq + 8 * s1) & 31);   // rotation kills bank conflicts
        #pragma unroll
        for (int q = 0; q < 4; ++q)
            w2r[jq * 4 + q] = loadf(w2, (base + q) * 128 + i1, mdt);
    }
    #pragma unroll
    for (int jq = 0; jq < 4; ++jq) {
        int base = 16 * s3 + ((4 * jq + 4 * s3) & 15);
        #pragma unroll
        for (int q = 0; q < 4; ++q)
            w3r[jq * 4 + q] = loadf(w3, (base + q) * 64 + i3, mdt);
    }
    const float bias1 = (s1 == 0) ? loadf(b1, i1, mdt) : 0.f;
    const float bias2 = (s1 == 0) ? loadf(b2, i1, mdt) : 0.f;
    const float bias3 = (s3 == 0) ? loadf(b3, i3, mdt) : 0.f;
    float g_ln = 0.f, b_ln = 0.f, zbr = 0.f, kar = 0.f;
    if (t < 64) {
        g_ln = loadf(lng, t, mdt); b_ln = loadf(lnb, t, mdt);
        zbr = z0f[b * 64 + t];
        zc[t] = zbr;
        zt_out[b * 12800 + t] = zbr;
    }
    if (t < 199) dts[t] = loadf(tvec, t + 1, mdt) - loadf(tvec, t, mdt);
    __syncthreads();

    #pragma unroll 1
    for (int step = 0; step < 199; ++step) {
        const float h = dts[step];
        #pragma unroll
        for (int e = 0; e < 4; ++e) {
            // layer1: h1 = silu(z @ W1 + b1)
            float a = 0.f;
            #pragma unroll
            for (int jq = 0; jq < 4; ++jq) {
                float4 zv = *(const float4*)&zc[16 * s1 + 4 * jq];
                a += zv.x * w1r[4 * jq + 0] + zv.y * w1r[4 * jq + 1]
                   + zv.z * w1r[4 * jq + 2] + zv.w * w1r[4 * jq + 3];
            }
            a += __shfl_xor(a, 1); a += __shfl_xor(a, 2);
            if (s1 == 0) { float v = a + bias1; h1f[i1] = v / (1.f + expf(-v)); }
            __syncthreads();

            // layer2: h2 = silu(h1 @ W2 + b2)
            a = 0.f;
            #pragma unroll
            for (int jq = 0; jq < 8; ++jq) {
                int idx = 32 * s1 + ((4 * jq + 8 * s1) & 31);
                float4 hv = *(const float4*)&h1f[idx];
                a += hv.x * w2r[4 * jq + 0] + hv.y * w2r[4 * jq + 1]
                   + hv.z * w2r[4 * jq + 2] + hv.w * w2r[4 * jq + 3];
            }
            a += __shfl_xor(a, 1); a += __shfl_xor(a, 2);
            if (s1 == 0) { float v = a + bias2; h2f[i1] = v / (1.f + expf(-v)); }
            __syncthreads();

            // layer3: dz = h2 @ W3 + b3
            a = 0.f;
            #pragma unroll
            for (int jq = 0; jq < 4; ++jq) {
                int idx = 16 * s3 + ((4 * jq + 4 * s3) & 15);
                float4 hv = *(const float4*)&h2f[idx];
                a += hv.x * w3r[4 * jq + 0] + hv.y * w3r[4 * jq + 1]
                   + hv.z * w3r[4 * jq + 2] + hv.w * w3r[4 * jq + 3];
            }
            a += __shfl_xor(a, 1); a += __shfl_xor(a, 2); a += __shfl_xor(a, 4);
            if (s3 == 0) dzf[i3] = a + bias3;
            __syncthreads();

            // layernorm (two-pass, mirrors reference) + RK4 bookkeeping
            if (t < 64) {
                float v = dzf[t];
                float sm = v;
                #pragma unroll
                for (int mm = 1; mm < 64; mm <<= 1) sm += __shfl_xor(sm, mm);
                float mean = sm * (1.f / 64.f);
                float d = v - mean;
                float sq = d * d;
                #pragma unroll
                for (int mm = 1; mm < 64; mm <<= 1) sq += __shfl_xor(sq, mm);
                float var = sq * (1.f / 64.f);
                float y = d / sqrtf(var + 1e-5f) * g_ln + b_ln;
                if (e == 0)      { kar = y;          zc[t] = zbr + 0.5f * h * y; }
                else if (e == 1) { kar += 2.f * y;   zc[t] = zbr + 0.5f * h * y; }
                else if (e == 2) { kar += 2.f * y;   zc[t] = zbr + h * y; }
                else {
                    kar += y;
                    float zn = zbr + (h * (1.f / 6.f)) * kar;
                    zt_out[b * 12800 + (step + 1) * 64 + t] = zn;
                    zd_out[b * 12736 + step * 64 + t] = (zn - zbr) / h;  // as reference
                    zbr = zn; zc[t] = zn;
                }
            }
            __syncthreads();
        }
    }
}

// ---------------------------------------------------------------------------
// Kernel 2.5: weight transpose + bf16 pack for the decoder GEMMs.
// Produces WT[n][k] (bf16) from W[k][n], with the K dim packed so that each
// 64-k block is laid out [lh(0..3)][half(0..1)][j(0..7)] — one wave's frag
// loads then consume whole 128B lines exactly once.
// ---------------------------------------------------------------------------
__global__ __launch_bounds__(256) void wt_kernel(
    const void* __restrict__ w1, const void* __restrict__ w2,
    const void* __restrict__ w3, const void* __restrict__ tvec,
    u16* __restrict__ wt1, u16* __restrict__ wt2, u16* __restrict__ wt3)
{
    __shared__ u16 tile[64][65];
    const bool m = detect_f32(tvec);
    const int b = blockIdx.x;
    const void* src; u16* dst; int K, kt, nt0;
    if (b < 8)       { src = w1; dst = wt1; K = 64;  kt = 0;          nt0 = b; }
    else if (b < 72) { src = w2; dst = wt2; K = 512; kt = (b-8) >> 3; nt0 = (b-8) & 7; }
    else             { src = w3; dst = wt3; K = 512; kt = (b-72) >> 3; nt0 = (b-72) & 7; }
    const int k0 = kt * 64, n0 = nt0 * 64;
    const int t = threadIdx.x;
    #pragma unroll
    for (int i = 0; i < 16; ++i) {
        int idx = t + 256 * i;                // 4096 elements per 64x64 tile
        int r = idx >> 6, c = idx & 63;       // r = k offset, c = n offset
        tile[r][c] = f2bf(loadf(src, (long)(k0 + r) * 512 + n0 + c, m));
    }
    __syncthreads();
    #pragma unroll
    for (int i = 0; i < 16; ++i) {
        int idx = t + 256 * i;
        int c = idx >> 6, r = idx & 63;       // c = n offset, r = k offset
        int pk = ((r >> 3) & 3) * 16 + ((r >> 5) & 1) * 8 + (r & 7);
        dst[(long)(n0 + c) * K + k0 + pk] = tile[r][c];
    }
}

// ---------------------------------------------------------------------------
// Kernel 3: decoder — bf16 MFMA GEMM chain, computed as C^T = W^T @ X^T so
// both operands and activation stores are contiguous in K.
//   block: 64 rows (BM=64), 256 threads = 4 waves; wave w owns n in
//   [w*128, w*128+128). acc = 8 n-tiles x 4 m-tiles x f32x4 = 128 VGPR.
//   Activations in LDS bf16 with XOR swizzle (byte ^= (row&7)<<4) to kill
//   the 1024B-row-stride bank conflict on ds_read_b128 (guide T2 / G4).
//   Layer 2 overwrites its input buffer in place (barrier-separated) so
//   LDS = 8K (X0) + 64K (X1) + 6K (bias) = 78KB -> 2 blocks/CU.
// ---------------------------------------------------------------------------
template<int K, int INROWB, bool RELU, bool TOLDS>
__device__ __forceinline__ void dec_layer(
    const u16* __restrict__ WT, const float* __restrict__ bl,
    const u16* Xin, u16* Xout, float* __restrict__ gout,
    long r0, int w, int lm, int lh)
{
    f32x4 acc[8][4];
    #pragma unroll
    for (int a = 0; a < 8; ++a)
        #pragma unroll
        for (int b = 0; b < 4; ++b) { f32x4 z4 = {0.f, 0.f, 0.f, 0.f}; acc[a][b] = z4; }

    #pragma unroll 1
    for (int kk2 = 0; kk2 < K / 64; ++kk2) {
        #pragma unroll
        for (int half = 0; half < 2; ++half) {
            const int kb = kk2 * 64 + half * 32 + lh * 8;   // logical k base
            bf8v bfr[4];
            #pragma unroll
            for (int mt = 0; mt < 4; ++mt) {
                int mr = mt * 16 + lm;
                int byte = mr * INROWB + kb * 2;
                bfr[mt] = *(const bf8v*)((const char*)Xin + (byte ^ ((mr & 7) << 4)));
            }
            bf8v afr[8];
            #pragma unroll
            for (int nt = 0; nt < 8; ++nt) {
                int n = w * 128 + nt * 16 + lm;
                // packed K layout: block kk2*64, then lh*16 + half*8
                afr[nt] = *(const bf8v*)&WT[(long)n * K + kk2 * 64 + lh * 16 + half * 8];
            }
            #pragma unroll
            for (int nt = 0; nt < 8; ++nt)
                #pragma unroll
                for (int mt = 0; mt < 4; ++mt)
                    acc[nt][mt] = __builtin_amdgcn_mfma_f32_16x16x32_bf16(
                        afr[nt], bfr[mt], acc[nt][mt], 0, 0, 0);
        }
    }
    __syncthreads();   // all Xin reads complete (required before in-place overwrite)

    // epilogue: bias (+relu), then bf16->LDS (8B packed) or fp32->global
    #pragma unroll
    for (int nt = 0; nt < 8; ++nt) {
        const int n0 = w * 128 + nt * 16 + lh * 4;     // D row = lh*4 + reg (m89)
        f32x4 bv = *(const f32x4*)&bl[n0];
        #pragma unroll
        for (int mt = 0; mt < 4; ++mt) {
            f32x4 v = acc[nt][mt];
            v.x += bv.x; v.y += bv.y; v.z += bv.z; v.w += bv.w;
            if (RELU) {
                v.x = fmaxf(v.x, 0.f); v.y = fmaxf(v.y, 0.f);
                v.z = fmaxf(v.z, 0.f); v.w = fmaxf(v.w, 0.f);
            }
            const int mr = mt * 16 + lm;               // D col = lane&15 (m89)
            if (TOLDS) {
                bf4v h;
                h.x = (short)f2bf(v.x); h.y = (short)f2bf(v.y);
                h.z = (short)f2bf(v.z); h.w = (short)f2bf(v.w);
                int byte = mr * 1024 + n0 * 2;
                *(bf4v*)((char*)Xout + (byte ^ ((mr & 7) << 4))) = h;
            } else {
                *(f32x4*)&gout[(r0 + mr) * 512 + n0] = v;
            }
        }
    }
    __syncthreads();   // Xout visible to all waves
}

__global__ __launch_bounds__(256, 2) void dec_kernel(
    const float* __restrict__ zt, const void* __restrict__ tvec,
    const u16* __restrict__ wt1, const u16* __restrict__ wt2,
    const u16* __restrict__ wt3,
    const void* __restrict__ b1, const void* __restrict__ b2,
    const void* __restrict__ b3,
    float* __restrict__ xhat)
{
    __shared__ __align__(16) u16 X0[64 * 64];     // z tile, bf16, row=128B, swizzled
    __shared__ __align__(16) u16 X1[64 * 512];    // activation, row=1024B, swizzled
    __shared__ __align__(16) float bl1[512], bl2[512], bl3[512];

    const bool m = detect_f32(tvec);
    const int t = threadIdx.x;
    const int l = t & 63, w = t >> 6;
    const int lm = l & 15, lh = l >> 4;
    const long r0 = (long)blockIdx.x * 64;

    // stage biases to LDS (fp32)
    bl1[t] = loadf(b1, t, m); bl1[t + 256] = loadf(b1, t + 256, m);
    bl2[t] = loadf(b2, t, m); bl2[t + 256] = loadf(b2, t + 256, m);
    bl3[t] = loadf(b3, t, m); bl3[t + 256] = loadf(b3, t + 256, m);

    // stage z rows (fp32 global) -> X0 bf16, swizzled
    {
        const int mrow = t >> 2;
        const int c0 = (t & 3) * 16;
        const float* zr = zt + (r0 + mrow) * 64 + c0;
        #pragma unroll
        for (int j = 0; j < 4; ++j) {
            float4 v = *(const float4*)(zr + 4 * j);
            bf4v h;
            h.x = (short)f2bf(v.x); h.y = (short)f2bf(v.y);
            h.z = (short)f2bf(v.z); h.w = (short)f2bf(v.w);
            int byte = mrow * 128 + (c0 + 4 * j) * 2;
            *(bf4v*)((char*)X0 + (byte ^ ((mrow & 7) << 4))) = h;
        }
    }
    __syncthreads();

    dec_layer< 64,  128, true,  true >(wt1, bl1, X0, X1, nullptr, r0, w, lm, lh);
    dec_layer<512, 1024, true,  true >(wt2, bl2, X1, X1, nullptr, r0, w, lm, lh);
    dec_layer<512, 1024, false, false>(wt3, bl3, X1, nullptr, xhat, r0, w, lm, lh);
}

// ---------------------------------------------------------------------------
extern "C" void kernel_launch(void* const* d_in, const int* in_sizes, int n_in,
                              void* d_out, int out_size, void* d_ws, size_t ws_size,
                              hipStream_t stream)
{
    float* out = (float*)d_out;
    float* z0f = (float*)d_ws;                                   // 64 KB
    u16* wt1 = (u16*)((char*)d_ws + 65536);                      // 512x64  bf16 = 64 KB
    u16* wt2 = (u16*)((char*)d_ws + 65536 + 65536);              // 512x512 bf16 = 512 KB
    u16* wt3 = (u16*)((char*)d_ws + 65536 + 65536 + 524288);     // 512x512 bf16 = 512 KB

    // decoder weight transpose/pack (independent of enc/ode)
    wt_kernel<<<136, 256, 0, stream>>>(
        d_in[21], d_in[23], d_in[25], d_in[1], wt1, wt2, wt3);

    enc_kernel<<<128, 512, 0, stream>>>(
        d_in[0], d_in[1], d_in[2], d_in[3], d_in[4], d_in[5], d_in[6],
        d_in[7], d_in[8], d_in[9], d_in[10], d_in[11], d_in[12],
        out, z0f);

    ode_kernel<<<256, 512, 0, stream>>>(
        d_in[1], d_in[13], d_in[14], d_in[15], d_in[16],
        d_in[17], d_in[18], d_in[19], d_in[20], z0f,
        out + ZT_OFF, out + ZD_OFF);

    dec_kernel<<<800, 256, 0, stream>>>(
        out + ZT_OFF, d_in[1], wt1, wt2, wt3,
        d_in[22], d_in[24], d_in[26], out);
}